// Round 11
// baseline (62.333 us; speedup 1.0000x reference)
//
#include <hip/hip_runtime.h>
#include <hip/hip_fp16.h>

#define DIM 1024
#define NB 8
#define CBLK 8
#define LSTRIDE 9  // half2 elements per row: 8 + 1 pad -> 36 B row stride
#define TAB_BYTES 1024  // first 1 KB of ws: packed W tables (2 passes x 3 x 16 u32)

typedef float vfloat4 __attribute__((ext_vector_type(4)));
typedef unsigned vuint4 __attribute__((ext_vector_type(4)));

// LDS tile: 1024 rows x (8+1) half2 = 36864 B -> 4 blocks/CU.
__device__ __forceinline__ int lidx(int r, int c) {
  return r * LSTRIDE + c;
}

__device__ __forceinline__ unsigned h2u(__half2 h) {
  union { __half2 h; unsigned u; } c; c.h = h; return c.u;
}
__device__ __forceinline__ __half2 u2h(unsigned u) {
  union { unsigned u; __half2 h; } c; c.u = u; return c.h;
}
// swap halves: (a,b) -> (b,a)
__device__ __forceinline__ __half2 h2swap(__half2 x) {
  unsigned u = h2u(x);
  return u2h((u >> 16) | (u << 16));
}

struct __align__(16) H2x4 { __half2 h[4]; };

// Packed complex 4x4 matvec, in place along `stride`. half2 = (re, im).
// y = W x : Wre2*x + Wimn*swap(x), Wre2=(Wre,Wre), Wimn=(-Wim,+Wim)
__device__ __forceinline__ void mv4p(__half2* v, const int stride,
                                     const unsigned (&Wre2)[4][4],
                                     const unsigned (&Wimn)[4][4]) {
  __half2 x0 = v[0], x1 = v[stride], x2 = v[2 * stride], x3 = v[3 * stride];
  __half2 s0 = h2swap(x0), s1 = h2swap(x1), s2 = h2swap(x2), s3 = h2swap(x3);
  #pragma unroll
  for (int p = 0; p < 4; ++p) {
    __half2 a = u2h(Wre2[p][0]) * x0;
    a = __hfma2(u2h(Wimn[p][0]), s0, a);
    a = __hfma2(u2h(Wre2[p][2]), x2, a);
    a = __hfma2(u2h(Wimn[p][2]), s2, a);
    __half2 b = u2h(Wre2[p][1]) * x1;
    b = __hfma2(u2h(Wimn[p][1]), s1, b);
    b = __hfma2(u2h(Wre2[p][3]), x3, b);
    b = __hfma2(u2h(Wimn[p][3]), s3, b);
    v[p * stride] = a + b;
  }
}

// Real-input packed variant: x[k] = (re,re); Wri=(Wre,Wim);
// y[p] = sum_k (Wre*re, Wim*re) — one packed op per term.
__device__ __forceinline__ void mv4rp(const __half2* x, __half2* y,
                                      const unsigned (&Wri)[4][4]) {
  #pragma unroll
  for (int p = 0; p < 4; ++p) {
    __half2 a = u2h(Wri[p][0]) * x[0];
    a = __hfma2(u2h(Wri[p][2]), x[2], a);
    __half2 b = u2h(Wri[p][1]) * x[1];
    b = __hfma2(u2h(Wri[p][3]), x[3], b);
    y[p] = a + b;
  }
}

// One-wave prep kernel: compute packed W tables for both passes into ws[0..96).
// Layout: tab[pass*48 + table*16 + j*4 + k], tables: 0=Wre2, 1=Wimn, 2=Wri.
// Removes ~250 VALU ops (incl. 6 sincos) from EVERY thread of the hot kernels.
__global__ void prep_W(const float* __restrict__ wgt, unsigned* __restrict__ tab) {
  if (threadIdx.x != 0) return;
  const float WMUL = 0.6324555320336759f;  // sqrt(0.4)
  float ca[6], sa[6];
  for (int i = 0; i < 6; ++i) {
    float h = wgt[i] * (0.5f * WMUL);
    ca[i] = cosf(h);
    sa[i] = sinf(h);
  }
  float R01[4][4], R34[4][4];
  {
    float a0[2][2] = {{ca[0], -sa[0]}, {sa[0], ca[0]}};
    float b0[2][2] = {{ca[1], -sa[1]}, {sa[1], ca[1]}};
    float a1[2][2] = {{ca[3], -sa[3]}, {sa[3], ca[3]}};
    float b1[2][2] = {{ca[4], -sa[4]}, {sa[4], ca[4]}};
    for (int i = 0; i < 4; ++i)
      for (int j = 0; j < 4; ++j) {
        R01[i][j] = a0[i >> 1][j >> 1] * b0[i & 1][j & 1];
        R34[i][j] = a1[i >> 1][j >> 1] * b1[i & 1][j & 1];
      }
  }
  float M2re[4][4], M2im[4][4];
  for (int k = 0; k < 4; ++k)
    for (int j = 0; j < 4; ++j) {
      M2re[k][j] = ca[2] * R01[k][j];
      M2im[k][j] = -sa[2] * R01[3 - k][j];
    }
  float M3re[4][4], M3im[4][4];
  for (int i = 0; i < 4; ++i)
    for (int j = 0; j < 4; ++j) {
      float rr = 0.f, ii = 0.f;
      for (int k = 0; k < 4; ++k) {
        rr += R34[i][k] * M2re[k][j];
        ii += R34[i][k] * M2im[k][j];
      }
      M3re[i][j] = rr;
      M3im[i][j] = ii;
    }
  for (int pass = 0; pass < 2; ++pass) {
    unsigned* t = tab + pass * 48;
    for (int k = 0; k < 4; ++k)
      for (int j = 0; j < 4; ++j) {
        float vre = ca[5] * M3re[k][j] + sa[5] * M3im[3 - k][j];
        float vim = ca[5] * M3im[k][j] - sa[5] * M3re[3 - k][j];
        // W[j][k] = V[k][j] (conj for pass 0)
        float wim = (pass == 0) ? -vim : vim;
        t[0 * 16 + j * 4 + k] = h2u(__floats2half2_rn(vre, vre));    // Wre2
        t[1 * 16 + j * 4 + k] = h2u(__floats2half2_rn(-wim, wim));   // Wimn
        t[2 * 16 + j * 4 + k] = h2u(__floats2half2_rn(vre, wim));    // Wri
      }
  }
}

// One pass over a 1024 x 8 column block; result written TRANSPOSED.
// R6/R10-proven 4-phase structure (3 barriers). R8/R9 lesson: fusing digit-0
// into the load phase poisons codegen (VGPR=36, SGPR=48, WRITE 161 MB, 2.5x
// slower). Do NOT restructure phase 0.
// W tables come pre-packed from prep_W via uniform loads (s_load -> SGPR).
// PASS 0: src = X (fp32, batch bg), dst = ws data region (complex fp16, bl)
// PASS 1: src = ws data region (complex fp16, bl), dst = d_out fp32 planes (bg)
// NOTE: min-waves/EU stays 4 — demanding 8 caps VGPRs at 64 and spills (R4).
template <int PASS>
__global__ __launch_bounds__(512, 4) void qpass(const void* __restrict__ srcv,
                                                const unsigned* __restrict__ tab,
                                                void* __restrict__ dstv,
                                                int batch0) {
  __shared__ __half2 tile[DIM * LSTRIDE];
  const int t = threadIdx.x;

  int B = blockIdx.x;
  int total = gridDim.x;
  int L;
  if ((total & 7) == 0) {
    int q = total >> 3;
    L = (B & 7) * q + (B >> 3);
  } else {
    L = B;
  }
  const int cg = L & 127;        // column group within batch (128 x 8 cols)
  const int bl = L >> 7;         // chunk-local batch (ws index)
  const int bg = batch0 + bl;    // global batch (x / out index)
  const int c0 = cg * CBLK;

  // Uniform table loads -> SGPRs (no per-thread trig, no readfirstlane).
  unsigned Wre2[4][4], Wimn[4][4], Wri[4][4];
  {
    const unsigned* wt = tab + PASS * 48;
    #pragma unroll
    for (int j = 0; j < 4; ++j)
      #pragma unroll
      for (int k = 0; k < 4; ++k) {
        Wre2[j][k] = wt[0 * 16 + j * 4 + k];
        Wimn[j][k] = wt[1 * 16 + j * 4 + k];
        Wri[j][k]  = wt[2 * 16 + j * 4 + k];
      }
  }

  // ---- load tile ---- (nontemporal: X / ws-in are read exactly once;
  // keep L2 lines for the ws tile pass 0 wrote)
  if (PASS == 0) {
    // real input staged as (re,re) so stage-1 digit uses 1-op/term mv4rp
    const float* s = (const float*)srcv + (size_t)bg * DIM * DIM + c0;
    #pragma unroll
    for (int it = 0; it < 4; ++it) {
      int u = it * 512 + t;            // 2048 float4 units
      int r = u >> 1, h = (u & 1) * 4;
      vfloat4 v = __builtin_nontemporal_load(
          reinterpret_cast<const vfloat4*>(s + (size_t)r * DIM + h));
      tile[lidx(r, h + 0)] = __half2half2(__float2half(v.x));
      tile[lidx(r, h + 1)] = __half2half2(__float2half(v.y));
      tile[lidx(r, h + 2)] = __half2half2(__float2half(v.z));
      tile[lidx(r, h + 3)] = __half2half2(__float2half(v.w));
    }
  } else {
    const __half2* s = (const __half2*)srcv + ((size_t)bl << 20) + c0;
    #pragma unroll
    for (int it = 0; it < 4; ++it) {
      int u = it * 512 + t;            // 2048 16B units
      int r = u >> 1, h = (u & 1) * 4;
      vuint4 v = __builtin_nontemporal_load(
          reinterpret_cast<const vuint4*>(s + (size_t)r * DIM + h));
      tile[lidx(r, h + 0)] = u2h(v.x);
      tile[lidx(r, h + 1)] = u2h(v.y);
      tile[lidx(r, h + 2)] = u2h(v.z);
      tile[lidx(r, h + 3)] = u2h(v.w);
    }
  }
  __syncthreads();

  // ---- stage 1: digits 0,1 (row strides 256, 64) ---- 1 item/thread
  {
    int c = t & 7, g = t >> 3;  // g in [0,64): fixed digits 2,3,4
    __half2 v[16];
    if (PASS == 0) {
      #pragma unroll
      for (int k0 = 0; k0 < 4; ++k0) {
        __half2 xs[4];
        #pragma unroll
        for (int k1 = 0; k1 < 4; ++k1)
          xs[k1] = tile[lidx(g + k0 * 256 + k1 * 64, c)];
        mv4rp(xs, &v[k0 * 4], Wri);                                  // digit 1
      }
    } else {
      #pragma unroll
      for (int k0 = 0; k0 < 4; ++k0)
        #pragma unroll
        for (int k1 = 0; k1 < 4; ++k1)
          v[k0 * 4 + k1] = tile[lidx(g + k0 * 256 + k1 * 64, c)];
      #pragma unroll
      for (int k0 = 0; k0 < 4; ++k0) mv4p(&v[k0 * 4], 1, Wre2, Wimn);  // digit 1
    }
    #pragma unroll
    for (int k1 = 0; k1 < 4; ++k1) mv4p(&v[k1], 4, Wre2, Wimn);        // digit 0
    #pragma unroll
    for (int k0 = 0; k0 < 4; ++k0)
      #pragma unroll
      for (int k1 = 0; k1 < 4; ++k1)
        tile[lidx(g + k0 * 256 + k1 * 64, c)] = v[k0 * 4 + k1];
  }
  __syncthreads();

  // ---- stage 2: digits 2,3 (row strides 16, 4) ---- 1 item/thread
  {
    int c = t & 7, g = t >> 3;
    int base = (g >> 2) * 64 + (g & 3);  // fixed digits 0,1 (g>>2) and 4 (g&3)
    __half2 v[16];
    #pragma unroll
    for (int k2 = 0; k2 < 4; ++k2)
      #pragma unroll
      for (int k3 = 0; k3 < 4; ++k3)
        v[k2 * 4 + k3] = tile[lidx(base + k2 * 16 + k3 * 4, c)];
    #pragma unroll
    for (int k2 = 0; k2 < 4; ++k2) mv4p(&v[k2 * 4], 1, Wre2, Wimn);  // digit 3
    #pragma unroll
    for (int k3 = 0; k3 < 4; ++k3) mv4p(&v[k3], 4, Wre2, Wimn);      // digit 2
    #pragma unroll
    for (int k2 = 0; k2 < 4; ++k2)
      #pragma unroll
      for (int k3 = 0; k3 < 4; ++k3)
        tile[lidx(base + k2 * 16 + k3 * 4, c)] = v[k2 * 4 + k3];
  }
  __syncthreads();

  // ---- stage 3: digit 4 (stride 1) + transposed writeout ----
  #pragma unroll
  for (int it = 0; it < 4; ++it) {
    int c = t & 7;
    int g = (t >> 3) + 64 * it;  // row group: rows 4g..4g+3
    __half2 v[4];
    #pragma unroll
    for (int k = 0; k < 4; ++k) v[k] = tile[lidx(4 * g + k, c)];
    mv4p(v, 1, Wre2, Wimn);
    if (PASS == 0) {
      // ws layout: complex-fp16 Tt[bl][k=c0+c][i=4g..4g+3]
      // (ws IS re-read by pass 1 -> keep cached, no nontemporal)
      __half2* d = (__half2*)dstv + ((size_t)bl << 20) + (size_t)(c0 + c) * DIM + 4 * g;
      H2x4 o;
      o.h[0] = v[0]; o.h[1] = v[1]; o.h[2] = v[2]; o.h[3] = v[3];
      *reinterpret_cast<H2x4*>(d) = o;
    } else {
      // out[0][bg][i=c0+c][j=4g..4g+3] (real), out[1][...] (imag)
      // final output never re-read -> nontemporal
      float2 f0 = __half22float2(v[0]), f1 = __half22float2(v[1]);
      float2 f2 = __half22float2(v[2]), f3 = __half22float2(v[3]);
      float* dr = (float*)dstv + ((size_t)bg << 20) + (size_t)(c0 + c) * DIM + 4 * g;
      float* di = dr + ((size_t)1 << 23);
      vfloat4 re = {f0.x, f1.x, f2.x, f3.x};
      vfloat4 im = {f0.y, f1.y, f2.y, f3.y};
      __builtin_nontemporal_store(re, reinterpret_cast<vfloat4*>(dr));
      __builtin_nontemporal_store(im, reinterpret_cast<vfloat4*>(di));
    }
  }
}

extern "C" void kernel_launch(void* const* d_in, const int* in_sizes, int n_in,
                              void* d_out, int out_size, void* d_ws, size_t ws_size,
                              hipStream_t stream) {
  const float* x = (const float*)d_in[0];
  const float* w = (const float*)d_in[1];

  unsigned* tab = (unsigned*)d_ws;                       // first 1 KB: W tables
  char* ws_data = (char*)d_ws + TAB_BYTES;               // batch tiles after

  prep_W<<<1, 64, 0, stream>>>(w, tab);

  const size_t per_batch = (size_t)DIM * DIM * sizeof(__half2);  // 4 MB fp16 complex
  int max_nb = (int)((ws_size - TAB_BYTES) / per_batch);
  if (max_nb > NB) max_nb = NB;
  if (max_nb < 1) max_nb = 1;  // assume ws >= 4 MB + 1 KB

  for (int b0 = 0; b0 < NB; b0 += max_nb) {
    int nb = NB - b0 < max_nb ? NB - b0 : max_nb;
    dim3 grid(128 * nb);
    qpass<0><<<grid, 512, 0, stream>>>(x, tab, ws_data, b0);
    qpass<1><<<grid, 512, 0, stream>>>(ws_data, tab, d_out, b0);
  }
}

// Round 12
// 53.399 us; speedup vs baseline: 1.1673x; 1.1673x over previous
//
#include <hip/hip_runtime.h>
#include <hip/hip_fp16.h>

#define DIM 1024
#define NB 8
#define CBLK 8
#define LSTRIDE 9  // half2 elements per row: 8 + 1 pad -> 36 B row stride

typedef float vfloat4 __attribute__((ext_vector_type(4)));  // native vec for nontemporal builtin

// LDS tile: 1024 rows x (8+1) half2 = 36864 B -> 4 blocks/CU.
__device__ __forceinline__ int lidx(int r, int c) {
  return r * LSTRIDE + c;
}

__device__ __forceinline__ unsigned rflu(unsigned x) {
  return (unsigned)__builtin_amdgcn_readfirstlane((int)x);
}
__device__ __forceinline__ unsigned h2u(__half2 h) {
  union { __half2 h; unsigned u; } c; c.h = h; return c.u;
}
__device__ __forceinline__ __half2 u2h(unsigned u) {
  union { unsigned u; __half2 h; } c; c.u = u; return c.h;
}
// swap halves: (a,b) -> (b,a)
__device__ __forceinline__ __half2 h2swap(__half2 x) {
  unsigned u = h2u(x);
  return u2h((u >> 16) | (u << 16));
}

struct __align__(16) H2x4 { __half2 h[4]; };

// Packed complex 4x4 matvec, in place along `stride`. half2 = (re, im).
// y = W x : Wre2*x + Wimn*swap(x), Wre2=(Wre,Wre), Wimn=(-Wim,+Wim)
__device__ __forceinline__ void mv4p(__half2* v, const int stride,
                                     const unsigned (&Wre2)[4][4],
                                     const unsigned (&Wimn)[4][4]) {
  __half2 x0 = v[0], x1 = v[stride], x2 = v[2 * stride], x3 = v[3 * stride];
  __half2 s0 = h2swap(x0), s1 = h2swap(x1), s2 = h2swap(x2), s3 = h2swap(x3);
  #pragma unroll
  for (int p = 0; p < 4; ++p) {
    __half2 a = u2h(Wre2[p][0]) * x0;
    a = __hfma2(u2h(Wimn[p][0]), s0, a);
    a = __hfma2(u2h(Wre2[p][2]), x2, a);
    a = __hfma2(u2h(Wimn[p][2]), s2, a);
    __half2 b = u2h(Wre2[p][1]) * x1;
    b = __hfma2(u2h(Wimn[p][1]), s1, b);
    b = __hfma2(u2h(Wre2[p][3]), x3, b);
    b = __hfma2(u2h(Wimn[p][3]), s3, b);
    v[p * stride] = a + b;
  }
}

// Real-input packed variant: x[k] = (re,re); Wri=(Wre,Wim);
// y[p] = sum_k (Wre*re, Wim*re) — one packed op per term.
__device__ __forceinline__ void mv4rp(const __half2* x, __half2* y,
                                      const unsigned (&Wri)[4][4]) {
  #pragma unroll
  for (int p = 0; p < 4; ++p) {
    __half2 a = u2h(Wri[p][0]) * x[0];
    a = __hfma2(u2h(Wri[p][2]), x[2], a);
    __half2 b = u2h(Wri[p][1]) * x[1];
    b = __hfma2(u2h(Wri[p][3]), x[3], b);
    y[p] = a + b;
  }
}

// Build W = V^dagger (pass 0) or V^T (pass 1); packed half2 tables in SGPRs.
// Computed per-thread: ~250 VALU ops hide under the load phase's HBM latency.
// R11 lesson: hoisting this to a prep kernel + global table loads REGRESSED
// (extra serialized launch + dependent loads at kernel start).
__device__ void compute_W(const float* __restrict__ wgt, int pass,
                          unsigned (&Wre2)[4][4], unsigned (&Wimn)[4][4],
                          unsigned (&Wri)[4][4]) {
  const float WMUL = 0.6324555320336759f;  // sqrt(0.4)
  float ca[6], sa[6];
  #pragma unroll
  for (int i = 0; i < 6; ++i) {
    float h = wgt[i] * (0.5f * WMUL);
    ca[i] = cosf(h);
    sa[i] = sinf(h);
  }
  float R01[4][4], R34[4][4];
  {
    float a0[2][2] = {{ca[0], -sa[0]}, {sa[0], ca[0]}};
    float b0[2][2] = {{ca[1], -sa[1]}, {sa[1], ca[1]}};
    float a1[2][2] = {{ca[3], -sa[3]}, {sa[3], ca[3]}};
    float b1[2][2] = {{ca[4], -sa[4]}, {sa[4], ca[4]}};
    #pragma unroll
    for (int i = 0; i < 4; ++i)
      #pragma unroll
      for (int j = 0; j < 4; ++j) {
        R01[i][j] = a0[i >> 1][j >> 1] * b0[i & 1][j & 1];
        R34[i][j] = a1[i >> 1][j >> 1] * b1[i & 1][j & 1];
      }
  }
  float M2re[4][4], M2im[4][4];
  #pragma unroll
  for (int k = 0; k < 4; ++k)
    #pragma unroll
    for (int j = 0; j < 4; ++j) {
      M2re[k][j] = ca[2] * R01[k][j];
      M2im[k][j] = -sa[2] * R01[3 - k][j];
    }
  float M3re[4][4], M3im[4][4];
  #pragma unroll
  for (int i = 0; i < 4; ++i)
    #pragma unroll
    for (int j = 0; j < 4; ++j) {
      float rr = 0.f, ii = 0.f;
      #pragma unroll
      for (int k = 0; k < 4; ++k) {
        rr += R34[i][k] * M2re[k][j];
        ii += R34[i][k] * M2im[k][j];
      }
      M3re[i][j] = rr;
      M3im[i][j] = ii;
    }
  #pragma unroll
  for (int k = 0; k < 4; ++k)
    #pragma unroll
    for (int j = 0; j < 4; ++j) {
      float vre = ca[5] * M3re[k][j] + sa[5] * M3im[3 - k][j];
      float vim = ca[5] * M3im[k][j] - sa[5] * M3re[3 - k][j];
      // W[j][k] = V[k][j] (conj for pass 0)
      float wim = (pass == 0) ? -vim : vim;
      Wre2[j][k] = rflu(h2u(__floats2half2_rn(vre, vre)));
      Wimn[j][k] = rflu(h2u(__floats2half2_rn(-wim, wim)));
      Wri[j][k] = rflu(h2u(__floats2half2_rn(vre, wim)));
    }
}

// One pass over a 1024 x 8 column block; result written TRANSPOSED.
// R6/R10-proven 4-phase structure (3 barriers). R8/R9 lesson: fusing digit-0
// into the load phase poisons codegen (VGPR=36, SGPR=48, WRITE 161 MB, 2.5x
// slower). Do NOT restructure phase 0. R11 lesson: do NOT nontemporal-hint
// the loads — X/ws-in reads hit L2 (pass-1 FETCH 16.5 MB << 32 MB data).
// PASS 0: src = X (fp32, batch bg), dst = ws (complex fp16, chunk-local bl)
// PASS 1: src = ws (complex fp16, bl), dst = d_out fp32 real/imag planes (bg)
// NOTE: min-waves/EU stays 4 — demanding 8 caps VGPRs at 64 and spills (R4).
template <int PASS>
__global__ __launch_bounds__(512, 4) void qpass(const void* __restrict__ srcv,
                                                const float* __restrict__ weight,
                                                void* __restrict__ dstv,
                                                int batch0) {
  __shared__ __half2 tile[DIM * LSTRIDE];
  const int t = threadIdx.x;

  int B = blockIdx.x;
  int total = gridDim.x;
  int L;
  if ((total & 7) == 0) {
    int q = total >> 3;
    L = (B & 7) * q + (B >> 3);
  } else {
    L = B;
  }
  const int cg = L & 127;        // column group within batch (128 x 8 cols)
  const int bl = L >> 7;         // chunk-local batch (ws index)
  const int bg = batch0 + bl;    // global batch (x / out index)
  const int c0 = cg * CBLK;

  unsigned Wre2[4][4], Wimn[4][4], Wri[4][4];
  compute_W(weight, PASS, Wre2, Wimn, Wri);

  // ---- load tile ----
  if (PASS == 0) {
    // real input staged as (re,re) so stage-1 digit uses 1-op/term mv4rp
    const float* s = (const float*)srcv + (size_t)bg * DIM * DIM + c0;
    #pragma unroll
    for (int it = 0; it < 4; ++it) {
      int u = it * 512 + t;            // 2048 float4 units
      int r = u >> 1, h = (u & 1) * 4;
      float4 v = *reinterpret_cast<const float4*>(s + (size_t)r * DIM + h);
      tile[lidx(r, h + 0)] = __half2half2(__float2half(v.x));
      tile[lidx(r, h + 1)] = __half2half2(__float2half(v.y));
      tile[lidx(r, h + 2)] = __half2half2(__float2half(v.z));
      tile[lidx(r, h + 3)] = __half2half2(__float2half(v.w));
    }
  } else {
    const __half2* s = (const __half2*)srcv + ((size_t)bl << 20) + c0;
    #pragma unroll
    for (int it = 0; it < 4; ++it) {
      int u = it * 512 + t;            // 2048 H2x4 units
      int r = u >> 1, h = (u & 1) * 4;
      H2x4 v = *reinterpret_cast<const H2x4*>(s + (size_t)r * DIM + h);
      tile[lidx(r, h + 0)] = v.h[0];
      tile[lidx(r, h + 1)] = v.h[1];
      tile[lidx(r, h + 2)] = v.h[2];
      tile[lidx(r, h + 3)] = v.h[3];
    }
  }
  __syncthreads();

  // ---- stage 1: digits 0,1 (row strides 256, 64) ---- 1 item/thread
  {
    int c = t & 7, g = t >> 3;  // g in [0,64): fixed digits 2,3,4
    __half2 v[16];
    if (PASS == 0) {
      #pragma unroll
      for (int k0 = 0; k0 < 4; ++k0) {
        __half2 xs[4];
        #pragma unroll
        for (int k1 = 0; k1 < 4; ++k1)
          xs[k1] = tile[lidx(g + k0 * 256 + k1 * 64, c)];
        mv4rp(xs, &v[k0 * 4], Wri);                                  // digit 1
      }
    } else {
      #pragma unroll
      for (int k0 = 0; k0 < 4; ++k0)
        #pragma unroll
        for (int k1 = 0; k1 < 4; ++k1)
          v[k0 * 4 + k1] = tile[lidx(g + k0 * 256 + k1 * 64, c)];
      #pragma unroll
      for (int k0 = 0; k0 < 4; ++k0) mv4p(&v[k0 * 4], 1, Wre2, Wimn);  // digit 1
    }
    #pragma unroll
    for (int k1 = 0; k1 < 4; ++k1) mv4p(&v[k1], 4, Wre2, Wimn);        // digit 0
    #pragma unroll
    for (int k0 = 0; k0 < 4; ++k0)
      #pragma unroll
      for (int k1 = 0; k1 < 4; ++k1)
        tile[lidx(g + k0 * 256 + k1 * 64, c)] = v[k0 * 4 + k1];
  }
  __syncthreads();

  // ---- stage 2: digits 2,3 (row strides 16, 4) ---- 1 item/thread
  {
    int c = t & 7, g = t >> 3;
    int base = (g >> 2) * 64 + (g & 3);  // fixed digits 0,1 (g>>2) and 4 (g&3)
    __half2 v[16];
    #pragma unroll
    for (int k2 = 0; k2 < 4; ++k2)
      #pragma unroll
      for (int k3 = 0; k3 < 4; ++k3)
        v[k2 * 4 + k3] = tile[lidx(base + k2 * 16 + k3 * 4, c)];
    #pragma unroll
    for (int k2 = 0; k2 < 4; ++k2) mv4p(&v[k2 * 4], 1, Wre2, Wimn);  // digit 3
    #pragma unroll
    for (int k3 = 0; k3 < 4; ++k3) mv4p(&v[k3], 4, Wre2, Wimn);      // digit 2
    #pragma unroll
    for (int k2 = 0; k2 < 4; ++k2)
      #pragma unroll
      for (int k3 = 0; k3 < 4; ++k3)
        tile[lidx(base + k2 * 16 + k3 * 4, c)] = v[k2 * 4 + k3];
  }
  __syncthreads();

  // ---- stage 3: digit 4 (stride 1) + transposed writeout ----
  #pragma unroll
  for (int it = 0; it < 4; ++it) {
    int c = t & 7;
    int g = (t >> 3) + 64 * it;  // row group: rows 4g..4g+3
    __half2 v[4];
    #pragma unroll
    for (int k = 0; k < 4; ++k) v[k] = tile[lidx(4 * g + k, c)];
    mv4p(v, 1, Wre2, Wimn);
    if (PASS == 0) {
      // ws layout: complex-fp16 Tt[bl][k=c0+c][i=4g..4g+3]
      // (ws IS re-read by pass 1 -> keep cached, no nontemporal)
      __half2* d = (__half2*)dstv + ((size_t)bl << 20) + (size_t)(c0 + c) * DIM + 4 * g;
      H2x4 o;
      o.h[0] = v[0]; o.h[1] = v[1]; o.h[2] = v[2]; o.h[3] = v[3];
      *reinterpret_cast<H2x4*>(d) = o;
    } else {
      // out[0][bg][i=c0+c][j=4g..4g+3] (real), out[1][...] (imag)
      // final output never re-read -> nontemporal, keep L2 for ws
      float2 f0 = __half22float2(v[0]), f1 = __half22float2(v[1]);
      float2 f2 = __half22float2(v[2]), f3 = __half22float2(v[3]);
      float* dr = (float*)dstv + ((size_t)bg << 20) + (size_t)(c0 + c) * DIM + 4 * g;
      float* di = dr + ((size_t)1 << 23);
      vfloat4 re = {f0.x, f1.x, f2.x, f3.x};
      vfloat4 im = {f0.y, f1.y, f2.y, f3.y};
      __builtin_nontemporal_store(re, reinterpret_cast<vfloat4*>(dr));
      __builtin_nontemporal_store(im, reinterpret_cast<vfloat4*>(di));
    }
  }
}

extern "C" void kernel_launch(void* const* d_in, const int* in_sizes, int n_in,
                              void* d_out, int out_size, void* d_ws, size_t ws_size,
                              hipStream_t stream) {
  const float* x = (const float*)d_in[0];
  const float* w = (const float*)d_in[1];

  const size_t per_batch = (size_t)DIM * DIM * sizeof(__half2);  // 4 MB complex fp16
  int max_nb = (int)(ws_size / per_batch);
  if (max_nb > NB) max_nb = NB;
  if (max_nb < 1) max_nb = 1;  // assume ws >= 4 MB

  for (int b0 = 0; b0 < NB; b0 += max_nb) {
    int nb = NB - b0 < max_nb ? NB - b0 : max_nb;
    dim3 grid(128 * nb);
    qpass<0><<<grid, 512, 0, stream>>>(x, w, d_ws, b0);
    qpass<1><<<grid, 512, 0, stream>>>(d_ws, w, d_out, b0);
  }
}